// Round 4
// baseline (255.590 us; speedup 1.0000x reference)
//
#include <hip/hip_runtime.h>

// ROI pooling / crop-and-resize, bilinear, half-pixel centers.
// fm: (64,64,128) fp32 NHWC; rois: (N,4) int32 [x1,y1,x2,y2]; out: (N,7,7,128) fp32.
//
// dur_us = harness poison-fill (~158us fixed) + kernel slice (~89us @ R3).
// R0-R3 post-mortem: VALU-hoist, SW-pipeline, fp16-reads all ~neutral.
// Accounted slice: ~40us writes + ~10us reads; the missing ~40us is the one
// invariant never varied: 10000 tiny blocks (39 block-slot turnovers/CU, each
// paying cold roi load + ramp + drain, only 8-deep hideable).
// This rev (single variable): persistent grid-stride blocks. NB=2048 =
// 256 CU x 8 resident -> every block launched exactly once, ~5 ROIs each,
// next ROI descriptor prefetched (s_load) during current ROI. Inner loop
// byte-identical to R3.

#define POOL 7
#define CH   128
#define FW   64
#define NPOS (POOL * POOL)
#define FM_ELEMS (FW * FW * CH)   // 524288 floats -> 1 MB fp16
#define NB 2048                   // persistent blocks: 256 CUs x 8 resident

typedef float    f32x4 __attribute__((ext_vector_type(4)));
typedef _Float16 f16x4 __attribute__((ext_vector_type(4)));

__device__ __forceinline__ float4 lerp4(float4 a, float4 b, float w) {
    float4 r;
    r.x = fmaf(w, b.x - a.x, a.x);
    r.y = fmaf(w, b.y - a.y, a.y);
    r.z = fmaf(w, b.z - a.z, a.z);
    r.w = fmaf(w, b.w - a.w, a.w);
    return r;
}

__device__ __forceinline__ float4 tofloat4(f16x4 h) {
    float4 r;
    r.x = (float)h[0]; r.y = (float)h[1]; r.z = (float)h[2]; r.w = (float)h[3];
    return r;
}

// ---- one-shot fm fp32 -> fp16 (512 blocks x 256 thr, one float4 each) ----
__global__ __launch_bounds__(256) void fm_convert_kernel(
    const float4* __restrict__ in, f16x4* __restrict__ outp)
{
    const int i = blockIdx.x * 256 + threadIdx.x;
    const float4 v = in[i];
    f16x4 h;
    h[0] = (_Float16)v.x; h[1] = (_Float16)v.y;
    h[2] = (_Float16)v.z; h[3] = (_Float16)v.w;
    outp[i] = h;
}

// ---- main kernel: persistent blocks, grid-stride over ROIs ----
__global__ __launch_bounds__(256, 8) void roi_pool_h16(
    const _Float16* __restrict__ fmh, const int* __restrict__ rois,
    float* __restrict__ out, int n_rois)
{
    __shared__ int4   tabi[NPOS];   // row0_byteoff, row1_byteoff, col0_byteoff, col1_byteoff
    __shared__ float2 tabf[NPOS];   // wy, wx

    const int tid  = threadIdx.x;
    const int posg = tid >> 5;        // 0..7: position group; pos = posg + 8*i
    const int lane = tid & 31;        // 0..31: channel group (f16x4 in / float4 out)
    const unsigned cb = (unsigned)(lane << 3);   // per-lane channel byte offset
    const char* fmb = (const char*)fmh;

    int n = blockIdx.x;
    if (n >= n_rois) return;

    // Prefetch first ROI descriptor (wave-uniform -> s_load).
    int4 r = *(const int4*)(rois + (size_t)n * 4);

    for (; n < n_rois; n += NB) {
        // Prefetch next ROI's descriptor during this ROI's work.
        const int nn = n + NB;
        int4 rn = r;
        if (nn < n_rois) rn = *(const int4*)(rois + (size_t)nn * 4);

        float4* outv = (float4*)(out + (size_t)n * (NPOS * CH)) + lane + posg * 32;

        if ((r.x | r.y | r.z | r.w) == 0) {
            float4 z = make_float4(0.f, 0.f, 0.f, 0.f);
#pragma unroll
            for (int i = 0; i < 6; ++i)
                __builtin_nontemporal_store(*(f32x4*)&z, (f32x4*)&outv[i * 256]);
            if (posg == 0)
                __builtin_nontemporal_store(*(f32x4*)&z, (f32x4*)&outv[6 * 256]);
            r = rn;
            continue;   // table untouched -> no barrier needed (block-uniform path)
        }

        const int hh = max(r.z - r.x, 1);   // note: r = (x1,y1,x2,y2)
        const int ww0 = max(r.z - r.x, 1);
        (void)ww0;

        const int rx1 = r.x, ry1 = r.y, rx2 = r.z, ry2 = r.w;
        const int hh2 = max(ry2 - ry1, 1);
        const int ww  = max(rx2 - rx1, 1);
        (void)hh;

        __syncthreads();   // previous ROI's readers done before table overwrite

        if (tid < NPOS) {
            const int py = tid / POOL;
            const int px = tid - py * POOL;
            const float hf = (float)hh2;
            const float wf = (float)ww;
            float yc = ((float)py + 0.5f) * hf / 7.0f - 0.5f;
            yc = fminf(fmaxf(yc, 0.0f), hf - 1.0f);
            float xc = ((float)px + 0.5f) * wf / 7.0f - 0.5f;
            xc = fminf(fmaxf(xc, 0.0f), wf - 1.0f);
            const int y0 = (int)floorf(yc);
            const int x0 = (int)floorf(xc);
            const int y1 = min(y0 + 1, hh2 - 1);
            const int x1 = min(x0 + 1, ww - 1);
            tabi[tid] = make_int4((y0 + ry1) * (FW * CH * 2),
                                  (y1 + ry1) * (FW * CH * 2),
                                  (x0 + rx1) * (CH * 2),
                                  (x1 + rx1) * (CH * 2));
            tabf[tid] = make_float2(yc - (float)y0, xc - (float)x0);
        }
        __syncthreads();

        // ---- 1-deep register prefetch, fully unrolled (pos = posg + 8*i) ----
        int4   e = tabi[posg];
        float2 w = tabf[posg];
        f16x4 g00 = *(const f16x4*)(fmb + ((unsigned)(e.x + e.z) + cb));
        f16x4 g01 = *(const f16x4*)(fmb + ((unsigned)(e.x + e.w) + cb));
        f16x4 g10 = *(const f16x4*)(fmb + ((unsigned)(e.y + e.z) + cb));
        f16x4 g11 = *(const f16x4*)(fmb + ((unsigned)(e.y + e.w) + cb));

#pragma unroll
        for (int i = 0; i < 6; ++i) {
            int4   en; float2 wn;
            f16x4 h00, h01, h10, h11;
            const bool has_next = (i < 5) || (posg == 0);
            if (has_next) {
                const int np = posg + 8 * (i + 1);
                en  = tabi[np];
                wn  = tabf[np];
                h00 = *(const f16x4*)(fmb + ((unsigned)(en.x + en.z) + cb));
                h01 = *(const f16x4*)(fmb + ((unsigned)(en.x + en.w) + cb));
                h10 = *(const f16x4*)(fmb + ((unsigned)(en.y + en.z) + cb));
                h11 = *(const f16x4*)(fmb + ((unsigned)(en.y + en.w) + cb));
            }
            const float4 top = lerp4(tofloat4(g00), tofloat4(g01), w.y);
            const float4 bot = lerp4(tofloat4(g10), tofloat4(g11), w.y);
            float4 res = lerp4(top, bot, w.x);
            __builtin_nontemporal_store(*(f32x4*)&res, (f32x4*)&outv[i * 256]);
            e = en; w = wn;
            g00 = h00; g01 = h01; g10 = h10; g11 = h11;
        }
        if (posg == 0) {
            const float4 top = lerp4(tofloat4(g00), tofloat4(g01), w.y);
            const float4 bot = lerp4(tofloat4(g10), tofloat4(g11), w.y);
            float4 res = lerp4(top, bot, w.x);
            __builtin_nontemporal_store(*(f32x4*)&res, (f32x4*)&outv[6 * 256]);
        }

        r = rn;
    }
}

// ---- f32 fallback (R2 kernel) if workspace too small ----
__global__ __launch_bounds__(256, 6) void roi_pool_f32(
    const float* __restrict__ fm, const int* __restrict__ rois,
    float* __restrict__ out, int n_rois)
{
    __shared__ int4   tabi[NPOS];
    __shared__ float2 tabf[NPOS];

    const int n = blockIdx.x;
    if (n >= n_rois) return;

    const int rx1 = rois[n * 4 + 0];
    const int ry1 = rois[n * 4 + 1];
    const int rx2 = rois[n * 4 + 2];
    const int ry2 = rois[n * 4 + 3];

    const int tid  = threadIdx.x;
    const int posg = tid >> 5;
    const int lane = tid & 31;

    float4* outv = (float4*)(out + (size_t)n * (NPOS * CH)) + lane + posg * 32;

    if ((rx1 | ry1 | rx2 | ry2) == 0) {
        float4 z = make_float4(0.f, 0.f, 0.f, 0.f);
#pragma unroll
        for (int i = 0; i < 6; ++i)
            __builtin_nontemporal_store(*(f32x4*)&z, (f32x4*)&outv[i * 256]);
        if (posg == 0)
            __builtin_nontemporal_store(*(f32x4*)&z, (f32x4*)&outv[6 * 256]);
        return;
    }

    const int hh = max(ry2 - ry1, 1);
    const int ww = max(rx2 - rx1, 1);

    if (tid < NPOS) {
        const int py = tid / POOL;
        const int px = tid - py * POOL;
        const float hf = (float)hh;
        const float wf = (float)ww;
        float yc = ((float)py + 0.5f) * hf / 7.0f - 0.5f;
        yc = fminf(fmaxf(yc, 0.0f), hf - 1.0f);
        float xc = ((float)px + 0.5f) * wf / 7.0f - 0.5f;
        xc = fminf(fmaxf(xc, 0.0f), wf - 1.0f);
        const int y0 = (int)floorf(yc);
        const int x0 = (int)floorf(xc);
        const int y1 = min(y0 + 1, hh - 1);
        const int x1 = min(x0 + 1, ww - 1);
        tabi[tid] = make_int4((y0 + ry1) * (FW * CH * 4),
                              (y1 + ry1) * (FW * CH * 4),
                              (x0 + rx1) * (CH * 4),
                              (x1 + rx1) * (CH * 4));
        tabf[tid] = make_float2(yc - (float)y0, xc - (float)x0);
    }
    __syncthreads();

    const unsigned cb = (unsigned)(lane << 4);
    const char* fmb = (const char*)fm;

    int4   e = tabi[posg];
    float2 w = tabf[posg];
    float4 g00 = *(const float4*)(fmb + ((unsigned)(e.x + e.z) + cb));
    float4 g01 = *(const float4*)(fmb + ((unsigned)(e.x + e.w) + cb));
    float4 g10 = *(const float4*)(fmb + ((unsigned)(e.y + e.z) + cb));
    float4 g11 = *(const float4*)(fmb + ((unsigned)(e.y + e.w) + cb));

#pragma unroll
    for (int i = 0; i < 6; ++i) {
        int4   en; float2 wn;
        float4 h00, h01, h10, h11;
        const bool has_next = (i < 5) || (posg == 0);
        if (has_next) {
            const int np = posg + 8 * (i + 1);
            en  = tabi[np];
            wn  = tabf[np];
            h00 = *(const float4*)(fmb + ((unsigned)(en.x + en.z) + cb));
            h01 = *(const float4*)(fmb + ((unsigned)(en.x + en.w) + cb));
            h10 = *(const float4*)(fmb + ((unsigned)(en.y + en.z) + cb));
            h11 = *(const float4*)(fmb + ((unsigned)(en.y + en.w) + cb));
        }
        const float4 top = lerp4(g00, g01, w.y);
        const float4 bot = lerp4(g10, g11, w.y);
        float4 res = lerp4(top, bot, w.x);
        __builtin_nontemporal_store(*(f32x4*)&res, (f32x4*)&outv[i * 256]);
        e = en; w = wn;
        g00 = h00; g01 = h01; g10 = h10; g11 = h11;
    }
    if (posg == 0) {
        const float4 top = lerp4(g00, g01, w.y);
        const float4 bot = lerp4(g10, g11, w.y);
        float4 res = lerp4(top, bot, w.x);
        __builtin_nontemporal_store(*(f32x4*)&res, (f32x4*)&outv[6 * 256]);
    }
}

extern "C" void kernel_launch(void* const* d_in, const int* in_sizes, int n_in,
                              void* d_out, int out_size, void* d_ws, size_t ws_size,
                              hipStream_t stream) {
    const float* fm   = (const float*)d_in[0];
    const int*   rois = (const int*)d_in[1];
    float*       out  = (float*)d_out;
    const int n_rois  = in_sizes[1] / 4;  // (1, N, 4) int32

    if (d_ws != nullptr && ws_size >= (size_t)FM_ELEMS * sizeof(_Float16)) {
        fm_convert_kernel<<<FM_ELEMS / (4 * 256), 256, 0, stream>>>(
            (const float4*)fm, (f16x4*)d_ws);
        const int nb = (n_rois < NB) ? n_rois : NB;
        roi_pool_h16<<<nb, 256, 0, stream>>>(
            (const _Float16*)d_ws, rois, out, n_rois);
    } else {
        roi_pool_f32<<<n_rois, 256, 0, stream>>>(fm, rois, out, n_rois);
    }
}

// Round 6
// 241.753 us; speedup vs baseline: 1.0572x; 1.0572x over previous
//
#include <hip/hip_runtime.h>

// ROI pooling / crop-and-resize, bilinear, half-pixel centers.
// fm: (64,64,128) fp32 NHWC; rois: (N,4) int32 [x1,y1,x2,y2]; out: (N,7,7,128) fp32.
//
// Measurement model (R0-R4 evidence): dur_us = fixed harness dispatches
// (>=160us: 1.004GB poison fill = 4x output, + resets) + kernel (<151us by
// top-5 argument; ~40-90us by roofline). Four structurally disjoint kernels
// all landed 248-256us -> fixed-cost dominated; kernel near its 40us write
// floor (251MB @ 6.35TB/s, rate proven by the fill itself).
// R5 single variable: revert nontemporal -> plain stores (the only knob whose
// introduction correlated with a regression; fill uses plain stores and hits
// 6.35TB/s via L2 writeback). Base = R3 (best measured: 247.3us).
// [R5 bench was an infra failure — container acquisition; identical resubmit.]

#define POOL 7
#define CH   128
#define FW   64
#define NPOS (POOL * POOL)
#define FM_ELEMS (FW * FW * CH)   // 524288 floats -> 1 MB fp16

typedef float    f32x4 __attribute__((ext_vector_type(4)));
typedef _Float16 f16x4 __attribute__((ext_vector_type(4)));

__device__ __forceinline__ float4 lerp4(float4 a, float4 b, float w) {
    float4 r;
    r.x = fmaf(w, b.x - a.x, a.x);
    r.y = fmaf(w, b.y - a.y, a.y);
    r.z = fmaf(w, b.z - a.z, a.z);
    r.w = fmaf(w, b.w - a.w, a.w);
    return r;
}

__device__ __forceinline__ float4 tofloat4(f16x4 h) {
    float4 r;
    r.x = (float)h[0]; r.y = (float)h[1]; r.z = (float)h[2]; r.w = (float)h[3];
    return r;
}

// ---- one-shot fm fp32 -> fp16 (512 blocks x 256 thr, one float4 each) ----
__global__ __launch_bounds__(256) void fm_convert_kernel(
    const float4* __restrict__ in, f16x4* __restrict__ outp)
{
    const int i = blockIdx.x * 256 + threadIdx.x;
    const float4 v = in[i];
    f16x4 h;
    h[0] = (_Float16)v.x; h[1] = (_Float16)v.y;
    h[2] = (_Float16)v.z; h[3] = (_Float16)v.w;
    outp[i] = h;
}

// ---- main kernel, fp16 gathers, plain (cached) stores ----
__global__ __launch_bounds__(256, 8) void roi_pool_h16(
    const _Float16* __restrict__ fmh, const int* __restrict__ rois,
    float* __restrict__ out, int n_rois)
{
    __shared__ int4   tabi[NPOS];   // row0_byteoff, row1_byteoff, col0_byteoff, col1_byteoff
    __shared__ float2 tabf[NPOS];   // wy, wx

    const int n = blockIdx.x;
    if (n >= n_rois) return;

    const int rx1 = rois[n * 4 + 0];
    const int ry1 = rois[n * 4 + 1];
    const int rx2 = rois[n * 4 + 2];
    const int ry2 = rois[n * 4 + 3];

    const int tid  = threadIdx.x;
    const int posg = tid >> 5;        // 0..7: position group; pos = posg + 8*i
    const int lane = tid & 31;        // 0..31: channel group (f16x4 in / float4 out)

    float4* outv = (float4*)(out + (size_t)n * (NPOS * CH)) + lane + posg * 32;

    if ((rx1 | ry1 | rx2 | ry2) == 0) {
        float4 z = make_float4(0.f, 0.f, 0.f, 0.f);
#pragma unroll
        for (int i = 0; i < 6; ++i)
            outv[i * 256] = z;
        if (posg == 0)
            outv[6 * 256] = z;
        return;
    }

    const int hh = max(ry2 - ry1, 1);
    const int ww = max(rx2 - rx1, 1);

    // One-time per-block table (byte offsets into the fp16 fm: 2 B/elem).
    if (tid < NPOS) {
        const int py = tid / POOL;
        const int px = tid - py * POOL;
        const float hf = (float)hh;
        const float wf = (float)ww;
        float yc = ((float)py + 0.5f) * hf / 7.0f - 0.5f;
        yc = fminf(fmaxf(yc, 0.0f), hf - 1.0f);
        float xc = ((float)px + 0.5f) * wf / 7.0f - 0.5f;
        xc = fminf(fmaxf(xc, 0.0f), wf - 1.0f);
        const int y0 = (int)floorf(yc);
        const int x0 = (int)floorf(xc);
        const int y1 = min(y0 + 1, hh - 1);
        const int x1 = min(x0 + 1, ww - 1);
        tabi[tid] = make_int4((y0 + ry1) * (FW * CH * 2),
                              (y1 + ry1) * (FW * CH * 2),
                              (x0 + rx1) * (CH * 2),
                              (x1 + rx1) * (CH * 2));
        tabf[tid] = make_float2(yc - (float)y0, xc - (float)x0);
    }
    __syncthreads();

    const unsigned cb = (unsigned)(lane << 3);   // per-lane channel byte offset (4 halfs)
    const char* fmb = (const char*)fmh;

    // ---- 1-deep register prefetch, fully unrolled (pos = posg + 8*i) ----
    int4   e = tabi[posg];
    float2 w = tabf[posg];
    f16x4 g00 = *(const f16x4*)(fmb + ((unsigned)(e.x + e.z) + cb));
    f16x4 g01 = *(const f16x4*)(fmb + ((unsigned)(e.x + e.w) + cb));
    f16x4 g10 = *(const f16x4*)(fmb + ((unsigned)(e.y + e.z) + cb));
    f16x4 g11 = *(const f16x4*)(fmb + ((unsigned)(e.y + e.w) + cb));

#pragma unroll
    for (int i = 0; i < 6; ++i) {
        int4   en; float2 wn;
        f16x4 h00, h01, h10, h11;
        const bool has_next = (i < 5) || (posg == 0);
        if (has_next) {
            const int np = posg + 8 * (i + 1);
            en  = tabi[np];
            wn  = tabf[np];
            h00 = *(const f16x4*)(fmb + ((unsigned)(en.x + en.z) + cb));
            h01 = *(const f16x4*)(fmb + ((unsigned)(en.x + en.w) + cb));
            h10 = *(const f16x4*)(fmb + ((unsigned)(en.y + en.z) + cb));
            h11 = *(const f16x4*)(fmb + ((unsigned)(en.y + en.w) + cb));
        }
        const float4 top = lerp4(tofloat4(g00), tofloat4(g01), w.y);
        const float4 bot = lerp4(tofloat4(g10), tofloat4(g11), w.y);
        float4 res = lerp4(top, bot, w.x);
        outv[i * 256] = res;
        e = en; w = wn;
        g00 = h00; g01 = h01; g10 = h10; g11 = h11;
    }
    if (posg == 0) {
        const float4 top = lerp4(tofloat4(g00), tofloat4(g01), w.y);
        const float4 bot = lerp4(tofloat4(g10), tofloat4(g11), w.y);
        float4 res = lerp4(top, bot, w.x);
        outv[6 * 256] = res;
    }
}

// ---- f32 fallback (plain stores) if workspace too small ----
__global__ __launch_bounds__(256, 6) void roi_pool_f32(
    const float* __restrict__ fm, const int* __restrict__ rois,
    float* __restrict__ out, int n_rois)
{
    __shared__ int4   tabi[NPOS];
    __shared__ float2 tabf[NPOS];

    const int n = blockIdx.x;
    if (n >= n_rois) return;

    const int rx1 = rois[n * 4 + 0];
    const int ry1 = rois[n * 4 + 1];
    const int rx2 = rois[n * 4 + 2];
    const int ry2 = rois[n * 4 + 3];

    const int tid  = threadIdx.x;
    const int posg = tid >> 5;
    const int lane = tid & 31;

    float4* outv = (float4*)(out + (size_t)n * (NPOS * CH)) + lane + posg * 32;

    if ((rx1 | ry1 | rx2 | ry2) == 0) {
        float4 z = make_float4(0.f, 0.f, 0.f, 0.f);
#pragma unroll
        for (int i = 0; i < 6; ++i)
            outv[i * 256] = z;
        if (posg == 0)
            outv[6 * 256] = z;
        return;
    }

    const int hh = max(ry2 - ry1, 1);
    const int ww = max(rx2 - rx1, 1);

    if (tid < NPOS) {
        const int py = tid / POOL;
        const int px = tid - py * POOL;
        const float hf = (float)hh;
        const float wf = (float)ww;
        float yc = ((float)py + 0.5f) * hf / 7.0f - 0.5f;
        yc = fminf(fmaxf(yc, 0.0f), hf - 1.0f);
        float xc = ((float)px + 0.5f) * wf / 7.0f - 0.5f;
        xc = fminf(fmaxf(xc, 0.0f), wf - 1.0f);
        const int y0 = (int)floorf(yc);
        const int x0 = (int)floorf(xc);
        const int y1 = min(y0 + 1, hh - 1);
        const int x1 = min(x0 + 1, ww - 1);
        tabi[tid] = make_int4((y0 + ry1) * (FW * CH * 4),
                              (y1 + ry1) * (FW * CH * 4),
                              (x0 + rx1) * (CH * 4),
                              (x1 + rx1) * (CH * 4));
        tabf[tid] = make_float2(yc - (float)y0, xc - (float)x0);
    }
    __syncthreads();

    const unsigned cb = (unsigned)(lane << 4);
    const char* fmb = (const char*)fm;

    int4   e = tabi[posg];
    float2 w = tabf[posg];
    float4 g00 = *(const float4*)(fmb + ((unsigned)(e.x + e.z) + cb));
    float4 g01 = *(const float4*)(fmb + ((unsigned)(e.x + e.w) + cb));
    float4 g10 = *(const float4*)(fmb + ((unsigned)(e.y + e.z) + cb));
    float4 g11 = *(const float4*)(fmb + ((unsigned)(e.y + e.w) + cb));

#pragma unroll
    for (int i = 0; i < 6; ++i) {
        int4   en; float2 wn;
        float4 h00, h01, h10, h11;
        const bool has_next = (i < 5) || (posg == 0);
        if (has_next) {
            const int np = posg + 8 * (i + 1);
            en  = tabi[np];
            wn  = tabf[np];
            h00 = *(const float4*)(fmb + ((unsigned)(en.x + en.z) + cb));
            h01 = *(const float4*)(fmb + ((unsigned)(en.x + en.w) + cb));
            h10 = *(const float4*)(fmb + ((unsigned)(en.y + en.z) + cb));
            h11 = *(const float4*)(fmb + ((unsigned)(en.y + en.w) + cb));
        }
        const float4 top = lerp4(g00, g01, w.y);
        const float4 bot = lerp4(g10, g11, w.y);
        float4 res = lerp4(top, bot, w.x);
        outv[i * 256] = res;
        e = en; w = wn;
        g00 = h00; g01 = h01; g10 = h10; g11 = h11;
    }
    if (posg == 0) {
        const float4 top = lerp4(g00, g01, w.y);
        const float4 bot = lerp4(g10, g11, w.y);
        float4 res = lerp4(top, bot, w.x);
        outv[6 * 256] = res;
    }
}

extern "C" void kernel_launch(void* const* d_in, const int* in_sizes, int n_in,
                              void* d_out, int out_size, void* d_ws, size_t ws_size,
                              hipStream_t stream) {
    const float* fm   = (const float*)d_in[0];
    const int*   rois = (const int*)d_in[1];
    float*       out  = (float*)d_out;
    const int n_rois  = in_sizes[1] / 4;  // (1, N, 4) int32

    if (d_ws != nullptr && ws_size >= (size_t)FM_ELEMS * sizeof(_Float16)) {
        fm_convert_kernel<<<FM_ELEMS / (4 * 256), 256, 0, stream>>>(
            (const float4*)fm, (f16x4*)d_ws);
        roi_pool_h16<<<n_rois, 256, 0, stream>>>(
            (const _Float16*)d_ws, rois, out, n_rois);
    } else {
        roi_pool_f32<<<n_rois, 256, 0, stream>>>(fm, rois, out, n_rois);
    }
}